// Round 10
// baseline (210.764 us; speedup 1.0000x reference)
//
#include <hip/hip_runtime.h>
#include <hip/hip_bf16.h>
#include <math.h>

#define V_N   6890
#define N_PTS 16384
#define D_IN  700
#define D_INP 704      // padded K for layer 1
#define D_HID 256
#define D_OUT 283
#define NCHUNK 32
#define CHUNK  216     // ceil(6890/32)
#define GAP_EPS 1e-4f  // combined fp32 error (ours + reference) ~1e-5 -> 10x margin

// ws layout (float units; all offsets *4 bytes, 16B aligned)
#define RINV_OFF 0              // V*9 -> 62016
#define KP4_OFF  62016          // V*4 -> 27584
#define RP4_OFF  89600          // V*4 -> 27584
#define KNN_OFF  117184        // 16384
#define CNT_OFF  133568        // 16
#define FLAG_OFF 133584        // 16384
#define PB4_OFF  149968        // NCHUNK*N float4 = 2097152 floats
#define WT1_OFF  2247120       // 90112
#define WT2_OFF  2337232       // 32768
#define WT3_OFF  2370000       // 32768
#define X_OFF    2402768       // 5767168
// end 8169936 floats ~= 32.7 MB

typedef __attribute__((ext_vector_type(8))) short short8;
typedef __attribute__((ext_vector_type(4))) float f32x4;

__device__ __forceinline__ unsigned short f2bf(float f) {
    unsigned int u = __builtin_bit_cast(unsigned int, f);
    u += 0x7fffu + ((u >> 16) & 1u);   // RNE
    return (unsigned short)(u >> 16);
}

// HW transcendental: sin(x) = v_sin_f32(fract(x/2pi)) -- 3 VALU ops vs ~100 libm.
__device__ __forceinline__ float fsin(float x) {
    return __builtin_amdgcn_sinf(__builtin_amdgcn_fractf(x * 0.15915494309189535f));
}
__device__ __forceinline__ float fcos(float x) {
    return __builtin_amdgcn_cosf(__builtin_amdgcn_fractf(x * 0.15915494309189535f));
}

__device__ __forceinline__ void glds16(const void* g, void* l) {
    __builtin_amdgcn_global_load_lds(
        (const __attribute__((address_space(1))) void*)g,
        (__attribute__((address_space(3))) void*)l, 16, 0, 0);
}

// ---------------- merged prep (blocks 0..26) + weight convert (blocks 27+) ----------------
#define PREP_BLOCKS 27
__global__ __launch_bounds__(256) void prep_wconv_kernel(
    const float* __restrict__ trans, const float* __restrict__ keyp,
    const float* __restrict__ restp,
    float* __restrict__ rinv, float4* __restrict__ kp4, float4* __restrict__ rp4,
    const float* __restrict__ W1, const float* __restrict__ W2,
    const float* __restrict__ W3, unsigned short* __restrict__ wt1,
    unsigned short* __restrict__ wt2, unsigned short* __restrict__ wt3,
    int* __restrict__ cnt)
{
    if (blockIdx.x == 0 && threadIdx.x == 0) cnt[0] = 0;
    if (blockIdx.x < PREP_BLOCKS) {
        int v = blockIdx.x * 256 + threadIdx.x;
        if (v >= V_N) return;
        float m[16];
#pragma unroll
        for (int i = 0; i < 16; ++i) m[i] = trans[i * V_N + v];

        float i0  =  m[5]*m[10]*m[15] - m[5]*m[11]*m[14] - m[9]*m[6]*m[15] + m[9]*m[7]*m[14] + m[13]*m[6]*m[11] - m[13]*m[7]*m[10];
        float i4  = -m[4]*m[10]*m[15] + m[4]*m[11]*m[14] + m[8]*m[6]*m[15] - m[8]*m[7]*m[14] - m[12]*m[6]*m[11] + m[12]*m[7]*m[10];
        float i8  =  m[4]*m[9]*m[15]  - m[4]*m[11]*m[13] - m[8]*m[5]*m[15] + m[8]*m[7]*m[13] + m[12]*m[5]*m[11] - m[12]*m[7]*m[9];
        float i12 = -m[4]*m[9]*m[14]  + m[4]*m[10]*m[13] + m[8]*m[5]*m[14] - m[8]*m[6]*m[13] - m[12]*m[5]*m[10] + m[12]*m[6]*m[9];
        float i1  = -m[1]*m[10]*m[15] + m[1]*m[11]*m[14] + m[9]*m[2]*m[15] - m[9]*m[3]*m[14] - m[13]*m[2]*m[11] + m[13]*m[3]*m[10];
        float i5  =  m[0]*m[10]*m[15] - m[0]*m[11]*m[14] - m[8]*m[2]*m[15] + m[8]*m[3]*m[14] + m[12]*m[2]*m[11] - m[12]*m[3]*m[10];
        float i9  = -m[0]*m[9]*m[15]  + m[0]*m[11]*m[13] + m[8]*m[1]*m[15] - m[8]*m[3]*m[13] - m[12]*m[1]*m[11] + m[12]*m[3]*m[9];
        float i2  =  m[1]*m[6]*m[15]  - m[1]*m[7]*m[14]  - m[5]*m[2]*m[15] + m[5]*m[3]*m[14] + m[13]*m[2]*m[7]  - m[13]*m[3]*m[6];
        float i6  = -m[0]*m[6]*m[15]  + m[0]*m[7]*m[14]  + m[4]*m[2]*m[15] - m[4]*m[3]*m[14] - m[12]*m[2]*m[7]  + m[12]*m[3]*m[6];
        float i10 =  m[0]*m[5]*m[15]  - m[0]*m[7]*m[13]  - m[4]*m[1]*m[15] + m[4]*m[3]*m[13] + m[12]*m[1]*m[7]  - m[12]*m[3]*m[5];

        float det = m[0]*i0 + m[1]*i4 + m[2]*i8 + m[3]*i12;
        float id = 1.0f / det;
        rinv[v*9+0] = i0*id;  rinv[v*9+1] = i1*id;  rinv[v*9+2] = i2*id;
        rinv[v*9+3] = i4*id;  rinv[v*9+4] = i5*id;  rinv[v*9+5] = i6*id;
        rinv[v*9+6] = i8*id;  rinv[v*9+7] = i9*id;  rinv[v*9+8] = i10*id;

        float kx = keyp[v*3], ky = keyp[v*3+1], kz = keyp[v*3+2];
        kp4[v] = make_float4(kx, ky, kz, kx*kx + ky*ky + kz*kz);
        rp4[v] = make_float4(restp[v*3], restp[v*3+1], restp[v*3+2], 0.0f);
    } else {
        int idx = (blockIdx.x - PREP_BLOCKS) * 256 + threadIdx.x;
        const int N1 = 256 * D_INP;
        const int N2 = 256 * 256;
        if (idx < N1) {
            int n = idx / D_INP, k = idx - n * D_INP;
            float v = (k < D_IN) ? W1[k * 256 + n] : 0.0f;
            wt1[n * D_INP + k] = f2bf(v);
        } else if (idx < N1 + N2) {
            int t = idx - N1;
            int n = t >> 8, k = t & 255;
            wt2[n * 256 + k] = f2bf(W2[k * 256 + n]);
        } else if (idx < N1 + 2 * N2) {
            int t = idx - N1 - N2;
            int n = t >> 8, k = t & 255;
            wt3[n * 256 + k] = f2bf(W3[k * 256 + n]);
        }
    }
}

// ---------------- KNN scan: branchless fp32, chunk-major output (coalesced) --------
__global__ __launch_bounds__(256) void knn_scan_kernel(
    const float* __restrict__ pts, const float4* __restrict__ kp4,
    float4* __restrict__ pb4)
{
    int tid = threadIdx.x;
    int n = blockIdx.x * 256 + tid;
    int c = blockIdx.y;
    int v0 = c * CHUNK;
    int v1 = min(V_N, v0 + CHUNK);

    float px2 = 2.0f * pts[n*6+0], py2 = 2.0f * pts[n*6+1], pz2 = 2.0f * pts[n*6+2];

    float m1 = 1e30f, m2 = 1e30f;
    int bi = 0x7fffffff;

#define KNN_STEP(kk, jj)                                            \
    {                                                               \
        float d = kk.w - (px2*kk.x + py2*kk.y + pz2*kk.z);          \
        bool lt = d < m1;                                           \
        m2 = lt ? m1 : fminf(m2, d);                                \
        bi = lt ? (jj) : bi;                                        \
        m1 = fminf(m1, d);                                          \
    }

    int j = v0;
    for (; j + 4 <= v1; j += 4) {
        float4 k0 = kp4[j], k1 = kp4[j+1], k2 = kp4[j+2], k3 = kp4[j+3];
        KNN_STEP(k0, j); KNN_STEP(k1, j+1); KNN_STEP(k2, j+2); KNN_STEP(k3, j+3);
    }
    for (; j < v1; ++j) {
        float4 k0 = kp4[j];
        KNN_STEP(k0, j);
    }
#undef KNN_STEP

    pb4[(size_t)c*N_PTS + n] = make_float4(m1, m2, __int_as_float(bi), 0.0f);
}

// ---------------- KNN reduce: merge chunks, certify gap, flag ambiguous --------
__global__ __launch_bounds__(256) void knn_reduce_kernel(
    const float4* __restrict__ pb4, int* __restrict__ knn,
    int* __restrict__ cnt, int* __restrict__ flag_list)
{
    int n = blockIdx.x * 256 + threadIdx.x;
    float m1 = 1e30f, m2 = 1e30f;
    int bi = 0x7fffffff;
#pragma unroll
    for (int c = 0; c < NCHUNK; ++c) {
        float4 P = pb4[(size_t)c*N_PTS + n];   // coalesced
        float b = P.x, b2 = P.y;
        int i = __float_as_int(P.z);
        float mx = fmaxf(m1, b);
        m2 = fminf(fminf(m2, b2), mx);
        bi = (b < m1) ? i : bi;      // ascending c => equal keeps lower chunk
        m1 = fminf(m1, b);
    }
    knn[n] = bi;
    if (m2 - m1 < GAP_EPS) {
        int s = atomicAdd(cnt, 1);
        flag_list[s] = n;
    }
}

// ---------------- KNN exact: fp64 rescan, one wave per flagged point (R6-proven) ----
__global__ __launch_bounds__(256) void knn_exact_kernel(
    const float* __restrict__ pts, const float4* __restrict__ kp4,
    const int* __restrict__ cnt, const int* __restrict__ flag_list,
    int* __restrict__ knn)
{
    int lane = threadIdx.x & 63;
    int gwave = (blockIdx.x * 256 + threadIdx.x) >> 6;
    int nwaves = gridDim.x * 4;
    int total = cnt[0];

    for (int it = gwave; it < total; it += nwaves) {
        int n = flag_list[it];
        double pxd = (double)pts[n*6+0], pyd = (double)pts[n*6+1], pzd = (double)pts[n*6+2];
        double ppd = pxd*pxd + pyd*pyd + pzd*pzd;
        double best = 1e300; int bi = 0x7fffffff;
        for (int j = lane; j < V_N; j += 64) {
            float4 k = kp4[j];
            double kx = (double)k.x, ky = (double)k.y, kz = (double)k.z;
            double d = ppd - 2.0*(pxd*kx + pyd*ky + pzd*kz) + (kx*kx + ky*ky + kz*kz);
            if (d < best || (d == best && j < bi)) { best = d; bi = j; }
        }
#pragma unroll
        for (int off = 32; off >= 1; off >>= 1) {
            double od = __shfl_xor(best, off);
            int    oi = __shfl_xor(bi, off);
            if (od < best || (od == best && oi < bi)) { best = od; bi = oi; }
        }
        if (lane == 0) knn[n] = bi;
    }
}

// ---------------- features v3: 8 points per wave, batched gathers ----------------
// Phase A: lanes (p=lane>>3, j=lane&7) gather neigh/kp4/rp4 for 8 points in 3
// VMEM instructions (56/64 lanes active), park vf in wave-private LDS rows (no
// barrier: intra-wave waitcnt only). Phase B: per point, dir via readfirstlane-
// forced SCALAR loads (zero TA traffic), posenc from LDS broadcasts, coalesced
// X/out stores.
__global__ __launch_bounds__(512) void feat_kernel(
    const float* __restrict__ pts, const float* __restrict__ keyp,
    const int* __restrict__ neigh, const float* __restrict__ latent,
    const float* __restrict__ rinv, const float4* __restrict__ kp4,
    const float4* __restrict__ rp4, const int* __restrict__ knn,
    unsigned short* __restrict__ X, float* __restrict__ out)
{
    __shared__ float s_vf[8][8][29];   // [wave][point][28 + pad] = 7.4 KB

    int t = threadIdx.x;
    int w = t >> 6, lane = t & 63;
    int p = lane >> 3, j = lane & 7;
    int n0 = blockIdx.x * 64 + w * 8;   // first point of this wave
    int np = n0 + p;                    // this lane's point

    // Phase A: batched gathers
    int k8 = knn[np];                   // 8 distinct values, 1 inst
    float px = pts[np*6+0], py = pts[np*6+1], pz = pts[np*6+2];

    int v7 = 0;
    if (j < 7) {
        v7 = neigh[k8*7 + j];           // 56 lanes, 1 inst
        float4 kq = kp4[v7];            // 16B gather, 1 inst
        float4 rq = rp4[v7];            // 16B gather, 1 inst
        float dx = px - kq.x, dy = py - kq.y, dz = pz - kq.z;
        s_vf[w][p][j*3+0] = rq.x;
        s_vf[w][p][j*3+1] = rq.y;
        s_vf[w][p][j*3+2] = rq.z;
        s_vf[w][p][21+j]  = sqrtf(dx*dx + dy*dy + dz*dz);
    }
    // no barrier: each wave reads only its own LDS rows (compiler inserts lgkmcnt)

    // Phase B: per-point posenc + stores
#pragma unroll
    for (int pp = 0; pp < 8; ++pp) {
        int n = n0 + pp;                                   // wave-uniform
        int kk = __builtin_amdgcn_readfirstlane(__shfl(k8, pp*8));   // SGPR

        // dir: pure scalar loads (kk, n uniform)
        float pxp = pts[n*6+0], pyp = pts[n*6+1], pzp = pts[n*6+2];
        float ddx = pxp - keyp[kk*3+0];
        float ddy = pyp - keyp[kk*3+1];
        float ddz = pzp - keyp[kk*3+2];
        const float* R = &rinv[kk*9];
        float d0 = R[0]*ddx + R[1]*ddy + R[2]*ddz;
        float d1 = R[3]*ddx + R[4]*ddy + R[5]*ddz;
        float d2 = R[6]*ddx + R[7]*ddy + R[8]*ddz;
        float nrm = fmaxf(sqrtf(d0*d0 + d1*d1 + d2*d2), 1e-12f);
        float dir0 = d0/nrm, dir1 = d1/nrm, dir2 = d2/nrm;

        // output tail (fp32): [dir(3), sin f-major (12), cos (12)]
        if (lane < 27) {
            float val;
            if (lane < 3) {
                val = (lane == 0) ? dir0 : (lane == 1) ? dir1 : dir2;
            } else {
                int tt = (lane < 15) ? lane - 3 : lane - 15;
                int m = tt % 3;
                float db = (m == 0) ? dir0 : (m == 1) ? dir1 : dir2;
                float a = db * (float)(1 << (tt/3));
                val = (lane < 15) ? fsin(a) : fcos(a);
            }
            out[(size_t)n*D_OUT + 256 + lane] = val;
        }

        // X row bf16, quad-per-lane; vf from wave-private LDS (broadcast-heavy)
#pragma unroll
        for (int it = 0; it < 3; ++it) {
            int base = it * 256 + (lane << 2);
            bool in_range = base < D_INP;
            int region = (base < 28) ? 0 : (base < 308) ? 1 : (base < 588) ? 2
                       : (base < 700) ? 3 : 4;

            int t0 = (region == 1) ? base - 28 : (region == 2) ? base - 308 : 0;
            int q = t0 / 28;
            int r = t0 - q * 28;
            float f0 = (float)(1 << q);
            float a[4];
#pragma unroll
            for (int jj = 0; jj < 4; ++jj) {
                int rj; float fj;
                if (region == 0) { rj = base + jj; fj = 1.0f; }
                else if (region <= 2) {
                    rj = r + jj; fj = f0;
                    if (rj >= 28) { rj -= 28; fj = f0 * 2.0f; }
                } else { rj = 0; fj = 0.0f; }
                a[jj] = s_vf[w][pp][rj] * fj;       // ds_read_b32
            }
            // latent neighbor index via full-exec shuffle (v7 valid at lanes pp*8+0..6)
            int idxc = (region == 3) ? (base - 588) >> 4 : 0;
            int vL = __shfl(v7, pp*8 + idxc);

            unsigned short r0, r1, r2, r3;
            if (region == 0) {
                r0 = f2bf(a[0]); r1 = f2bf(a[1]); r2 = f2bf(a[2]); r3 = f2bf(a[3]);
            } else if (region == 1) {
                r0 = f2bf(fsin(a[0])); r1 = f2bf(fsin(a[1]));
                r2 = f2bf(fsin(a[2])); r3 = f2bf(fsin(a[3]));
            } else if (region == 2) {
                r0 = f2bf(fcos(a[0])); r1 = f2bf(fcos(a[1]));
                r2 = f2bf(fcos(a[2])); r3 = f2bf(fcos(a[3]));
            } else if (region == 3) {
                int t3 = base - 588;
                float4 lv = *(const float4*)&latent[vL * 16 + (t3 & 15)];
                r0 = f2bf(lv.x); r1 = f2bf(lv.y); r2 = f2bf(lv.z); r3 = f2bf(lv.w);
            } else {
                r0 = r1 = r2 = r3 = 0;
            }
            if (in_range)
                *(ushort4*)&X[(size_t)n * D_INP + base] = make_ushort4(r0, r1, r2, r3);
        }
    }
}

// ---------------- fused 3-layer MLP: 64 rows/block through all layers ----------------
#define HLD 264
__global__ __launch_bounds__(512) void mlp_kernel(
    const unsigned short* __restrict__ X,
    const unsigned short* __restrict__ wt1,
    const unsigned short* __restrict__ wt2,
    const unsigned short* __restrict__ wt3,
    const float* __restrict__ b1, const float* __restrict__ b2,
    const float* __restrict__ b3, float* __restrict__ out)
{
    __shared__ unsigned short As[64 * 32];     // 4 KB
    __shared__ unsigned short Ws[256 * 32];    // 16 KB
    __shared__ unsigned short H1[64 * HLD];    // 33 KB
    __shared__ unsigned short H2[64 * HLD];    // 33 KB

    int t = threadIdx.x, l = t & 63, w = t >> 6;
    int bm = blockIdx.x * 64;
    int mbase = (w >> 2) * 32, nbase = (w & 3) * 64;
    int lrow = l & 15, lk = (l >> 4) * 8;
    int col0 = l & 15, rquad = (l >> 4) * 4;

    f32x4 acc[2][4];
    short8 af[2], bf[4];

    // layer 1: X[704] @ wt1^T -> relu -> H1
#pragma unroll
    for (int mi = 0; mi < 2; ++mi)
#pragma unroll
        for (int ni = 0; ni < 4; ++ni) acc[mi][ni] = {0.f, 0.f, 0.f, 0.f};

    for (int k0 = 0; k0 < D_INP; k0 += 32) {
        if (t < 256)
            glds16(X + (size_t)(bm + (t >> 2)) * D_INP + k0 + (t & 3) * 8,
                   (char*)As + t * 16);
#pragma unroll
        for (int i = 0; i < 2; ++i) {
            int c = i * 512 + t;
            glds16(wt1 + (size_t)(c >> 2) * D_INP + k0 + (c & 3) * 8,
                   (char*)Ws + (size_t)c * 16);
        }
        __syncthreads();
#pragma unroll
        for (int mi = 0; mi < 2; ++mi)
            af[mi] = *(const short8*)&As[(mbase + mi * 16 + lrow) * 32 + lk];
#pragma unroll
        for (int ni = 0; ni < 4; ++ni)
            bf[ni] = *(const short8*)&Ws[(nbase + ni * 16 + lrow) * 32 + lk];
#pragma unroll
        for (int mi = 0; mi < 2; ++mi)
#pragma unroll
            for (int ni = 0; ni < 4; ++ni)
                acc[mi][ni] = __builtin_amdgcn_mfma_f32_16x16x32_bf16(
                    af[mi], bf[ni], acc[mi][ni], 0, 0, 0);
        __syncthreads();
    }
#pragma unroll
    for (int mi = 0; mi < 2; ++mi)
#pragma unroll
        for (int ni = 0; ni < 4; ++ni) {
            int col = nbase + ni * 16 + col0;
            float bv = b1[col];
#pragma unroll
            for (int r = 0; r < 4; ++r) {
                int row = mbase + mi * 16 + rquad + r;
                H1[row * HLD + col] = f2bf(fmaxf(acc[mi][ni][r] + bv, 0.0f));
            }
        }
    __syncthreads();

    // layer 2: H1 @ wt2^T -> relu -> H2
#pragma unroll
    for (int mi = 0; mi < 2; ++mi)
#pragma unroll
        for (int ni = 0; ni < 4; ++ni) acc[mi][ni] = {0.f, 0.f, 0.f, 0.f};

    for (int k0 = 0; k0 < D_HID; k0 += 32) {
#pragma unroll
        for (int i = 0; i < 2; ++i) {
            int c = i * 512 + t;
            glds16(wt2 + (size_t)(c >> 2) * D_HID + k0 + (c & 3) * 8,
                   (char*)Ws + (size_t)c * 16);
        }
        __syncthreads();
#pragma unroll
        for (int mi = 0; mi < 2; ++mi)
            af[mi] = *(const short8*)&H1[(mbase + mi * 16 + lrow) * HLD + k0 + lk];
#pragma unroll
        for (int ni = 0; ni < 4; ++ni)
            bf[ni] = *(const short8*)&Ws[(nbase + ni * 16 + lrow) * 32 + lk];
#pragma unroll
        for (int mi = 0; mi < 2; ++mi)
#pragma unroll
            for (int ni = 0; ni < 4; ++ni)
                acc[mi][ni] = __builtin_amdgcn_mfma_f32_16x16x32_bf16(
                    af[mi], bf[ni], acc[mi][ni], 0, 0, 0);
        __syncthreads();
    }
#pragma unroll
    for (int mi = 0; mi < 2; ++mi)
#pragma unroll
        for (int ni = 0; ni < 4; ++ni) {
            int col = nbase + ni * 16 + col0;
            float bv = b2[col];
#pragma unroll
            for (int r = 0; r < 4; ++r) {
                int row = mbase + mi * 16 + rquad + r;
                H2[row * HLD + col] = f2bf(fmaxf(acc[mi][ni][r] + bv, 0.0f));
            }
        }
    __syncthreads();

    // layer 3: H2 @ wt3^T + b3 -> out (fp32)
#pragma unroll
    for (int mi = 0; mi < 2; ++mi)
#pragma unroll
        for (int ni = 0; ni < 4; ++ni) acc[mi][ni] = {0.f, 0.f, 0.f, 0.f};

    for (int k0 = 0; k0 < D_HID; k0 += 32) {
#pragma unroll
        for (int i = 0; i < 2; ++i) {
            int c = i * 512 + t;
            glds16(wt3 + (size_t)(c >> 2) * D_HID + k0 + (c & 3) * 8,
                   (char*)Ws + (size_t)c * 16);
        }
        __syncthreads();
#pragma unroll
        for (int mi = 0; mi < 2; ++mi)
            af[mi] = *(const short8*)&H2[(mbase + mi * 16 + lrow) * HLD + k0 + lk];
#pragma unroll
        for (int ni = 0; ni < 4; ++ni)
            bf[ni] = *(const short8*)&Ws[(nbase + ni * 16 + lrow) * 32 + lk];
#pragma unroll
        for (int mi = 0; mi < 2; ++mi)
#pragma unroll
            for (int ni = 0; ni < 4; ++ni)
                acc[mi][ni] = __builtin_amdgcn_mfma_f32_16x16x32_bf16(
                    af[mi], bf[ni], acc[mi][ni], 0, 0, 0);
        __syncthreads();
    }
#pragma unroll
    for (int mi = 0; mi < 2; ++mi)
#pragma unroll
        for (int ni = 0; ni < 4; ++ni) {
            int col = nbase + ni * 16 + col0;
            float bv = b3[col];
#pragma unroll
            for (int r = 0; r < 4; ++r) {
                int row = bm + mbase + mi * 16 + rquad + r;
                out[(size_t)row * D_OUT + col] = acc[mi][ni][r] + bv;
            }
        }
}

extern "C" void kernel_launch(void* const* d_in, const int* in_sizes, int n_in,
                              void* d_out, int out_size, void* d_ws, size_t ws_size,
                              hipStream_t stream) {
    const float* pts    = (const float*)d_in[0];
    const float* keyp   = (const float*)d_in[1];
    const float* trans  = (const float*)d_in[2];
    const int*   neigh  = (const int*)d_in[3];
    const float* restp  = (const float*)d_in[4];
    const float* latent = (const float*)d_in[5];
    const float* W1     = (const float*)d_in[6];
    const float* b1     = (const float*)d_in[7];
    const float* W2     = (const float*)d_in[8];
    const float* b2     = (const float*)d_in[9];
    const float* W3     = (const float*)d_in[10];
    const float* b3     = (const float*)d_in[11];
    float* out = (float*)d_out;

    float* wsf = (float*)d_ws;
    float*          rinv = wsf + RINV_OFF;
    float4*         kp4  = (float4*)(wsf + KP4_OFF);
    float4*         rp4  = (float4*)(wsf + RP4_OFF);
    int*            knn  = (int*)(wsf + KNN_OFF);
    int*            cnt  = (int*)(wsf + CNT_OFF);
    int*            flg  = (int*)(wsf + FLAG_OFF);
    float4*         pb4  = (float4*)(wsf + PB4_OFF);
    unsigned short* wt1  = (unsigned short*)(wsf + WT1_OFF);
    unsigned short* wt2  = (unsigned short*)(wsf + WT2_OFF);
    unsigned short* wt3  = (unsigned short*)(wsf + WT3_OFF);
    unsigned short* X    = (unsigned short*)(wsf + X_OFF);

    int wconv_blocks = (256*D_INP + 2*256*256 + 255) / 256;
    prep_wconv_kernel<<<PREP_BLOCKS + wconv_blocks, 256, 0, stream>>>(
        trans, keyp, restp, rinv, kp4, rp4, W1, W2, W3, wt1, wt2, wt3, cnt);
    knn_scan_kernel<<<dim3(N_PTS/256, NCHUNK), 256, 0, stream>>>(pts, kp4, pb4);
    knn_reduce_kernel<<<N_PTS/256, 256, 0, stream>>>(pb4, knn, cnt, flg);
    knn_exact_kernel<<<128, 256, 0, stream>>>(pts, kp4, cnt, flg, knn);
    feat_kernel<<<N_PTS/64, 512, 0, stream>>>(pts, keyp, neigh, latent, rinv,
                                              kp4, rp4, knn, X, out);
    mlp_kernel<<<N_PTS/64, 512, 0, stream>>>(X, wt1, wt2, wt3, b1, b2, b3, out);
}

// Round 11
// 205.384 us; speedup vs baseline: 1.0262x; 1.0262x over previous
//
#include <hip/hip_runtime.h>
#include <hip/hip_bf16.h>
#include <math.h>

#define V_N   6890
#define N_PTS 16384
#define D_IN  700
#define D_INP 704      // padded K for layer 1
#define D_HID 256
#define D_OUT 283
#define NCHUNK 32
#define CHUNK  216     // ceil(6890/32)
#define GAP_EPS 1e-4f  // combined fp32 error (ours + reference) ~1e-5 -> 10x margin

// ws layout (float units; all offsets *4 bytes, 16B aligned)
#define RINV4_OFF 0             // V*12 -> 82688 (padded 3x float4 rows)
#define KP4_OFF   82688         // V*4 -> 27584
#define RP4_OFF   110272        // V*4 -> 27584
#define KNN_OFF   137856        // 16384
#define CNT_OFF   154240        // 16
#define FLAG_OFF  154256        // 16384
#define PB4_OFF   170640        // NCHUNK*N float4 = 2097152 floats
#define WT1_OFF   2267792       // 90112
#define WT2_OFF   2357904       // 32768
#define WT3_OFF   2390672       // 32768
#define X_OFF     2423440       // 5767168
// end 8190608 floats ~= 32.8 MB

typedef __attribute__((ext_vector_type(8))) short short8;
typedef __attribute__((ext_vector_type(4))) float f32x4;

__device__ __forceinline__ unsigned short f2bf(float f) {
    unsigned int u = __builtin_bit_cast(unsigned int, f);
    u += 0x7fffu + ((u >> 16) & 1u);   // RNE
    return (unsigned short)(u >> 16);
}

// HW transcendental: sin(x) = v_sin_f32(fract(x/2pi)) -- 3 VALU ops vs ~100 libm.
__device__ __forceinline__ float fsin(float x) {
    return __builtin_amdgcn_sinf(__builtin_amdgcn_fractf(x * 0.15915494309189535f));
}
__device__ __forceinline__ float fcos(float x) {
    return __builtin_amdgcn_cosf(__builtin_amdgcn_fractf(x * 0.15915494309189535f));
}

__device__ __forceinline__ void glds16(const void* g, void* l) {
    __builtin_amdgcn_global_load_lds(
        (const __attribute__((address_space(1))) void*)g,
        (__attribute__((address_space(3))) void*)l, 16, 0, 0);
}

// ---------------- merged prep (blocks 0..26) + weight convert (blocks 27+) ----------------
#define PREP_BLOCKS 27
__global__ __launch_bounds__(256) void prep_wconv_kernel(
    const float* __restrict__ trans, const float* __restrict__ keyp,
    const float* __restrict__ restp,
    float4* __restrict__ rinv4, float4* __restrict__ kp4, float4* __restrict__ rp4,
    const float* __restrict__ W1, const float* __restrict__ W2,
    const float* __restrict__ W3, unsigned short* __restrict__ wt1,
    unsigned short* __restrict__ wt2, unsigned short* __restrict__ wt3,
    int* __restrict__ cnt)
{
    if (blockIdx.x == 0 && threadIdx.x == 0) cnt[0] = 0;
    if (blockIdx.x < PREP_BLOCKS) {
        int v = blockIdx.x * 256 + threadIdx.x;
        if (v >= V_N) return;
        float m[16];
#pragma unroll
        for (int i = 0; i < 16; ++i) m[i] = trans[i * V_N + v];

        float i0  =  m[5]*m[10]*m[15] - m[5]*m[11]*m[14] - m[9]*m[6]*m[15] + m[9]*m[7]*m[14] + m[13]*m[6]*m[11] - m[13]*m[7]*m[10];
        float i4  = -m[4]*m[10]*m[15] + m[4]*m[11]*m[14] + m[8]*m[6]*m[15] - m[8]*m[7]*m[14] - m[12]*m[6]*m[11] + m[12]*m[7]*m[10];
        float i8  =  m[4]*m[9]*m[15]  - m[4]*m[11]*m[13] - m[8]*m[5]*m[15] + m[8]*m[7]*m[13] + m[12]*m[5]*m[11] - m[12]*m[7]*m[9];
        float i12 = -m[4]*m[9]*m[14]  + m[4]*m[10]*m[13] + m[8]*m[5]*m[14] - m[8]*m[6]*m[13] - m[12]*m[5]*m[10] + m[12]*m[6]*m[9];
        float i1  = -m[1]*m[10]*m[15] + m[1]*m[11]*m[14] + m[9]*m[2]*m[15] - m[9]*m[3]*m[14] - m[13]*m[2]*m[11] + m[13]*m[3]*m[10];
        float i5  =  m[0]*m[10]*m[15] - m[0]*m[11]*m[14] - m[8]*m[2]*m[15] + m[8]*m[3]*m[14] + m[12]*m[2]*m[11] - m[12]*m[3]*m[10];
        float i9  = -m[0]*m[9]*m[15]  + m[0]*m[11]*m[13] + m[8]*m[1]*m[15] - m[8]*m[3]*m[13] - m[12]*m[1]*m[11] + m[12]*m[3]*m[9];
        float i2  =  m[1]*m[6]*m[15]  - m[1]*m[7]*m[14]  - m[5]*m[2]*m[15] + m[5]*m[3]*m[14] + m[13]*m[2]*m[7]  - m[13]*m[3]*m[6];
        float i6  = -m[0]*m[6]*m[15]  + m[0]*m[7]*m[14]  + m[4]*m[2]*m[15] - m[4]*m[3]*m[14] - m[12]*m[2]*m[7]  + m[12]*m[3]*m[6];
        float i10 =  m[0]*m[5]*m[15]  - m[0]*m[7]*m[13]  - m[4]*m[1]*m[15] + m[4]*m[3]*m[13] + m[12]*m[1]*m[7]  - m[12]*m[3]*m[5];

        float det = m[0]*i0 + m[1]*i4 + m[2]*i8 + m[3]*i12;
        float id = 1.0f / det;
        // row-major 3x3 packed into 3 float4 rows: (r0 r1 r2 r3)(r4 r5 r6 r7)(r8 - - -)
        rinv4[v*3+0] = make_float4(i0*id, i1*id, i2*id, i4*id);
        rinv4[v*3+1] = make_float4(i5*id, i6*id, i8*id, i9*id);
        rinv4[v*3+2] = make_float4(i10*id, 0.0f, 0.0f, 0.0f);

        float kx = keyp[v*3], ky = keyp[v*3+1], kz = keyp[v*3+2];
        kp4[v] = make_float4(kx, ky, kz, kx*kx + ky*ky + kz*kz);
        rp4[v] = make_float4(restp[v*3], restp[v*3+1], restp[v*3+2], 0.0f);
    } else {
        int idx = (blockIdx.x - PREP_BLOCKS) * 256 + threadIdx.x;
        const int N1 = 256 * D_INP;
        const int N2 = 256 * 256;
        if (idx < N1) {
            int n = idx / D_INP, k = idx - n * D_INP;
            float v = (k < D_IN) ? W1[k * 256 + n] : 0.0f;
            wt1[n * D_INP + k] = f2bf(v);
        } else if (idx < N1 + N2) {
            int t = idx - N1;
            int n = t >> 8, k = t & 255;
            wt2[n * 256 + k] = f2bf(W2[k * 256 + n]);
        } else if (idx < N1 + 2 * N2) {
            int t = idx - N1 - N2;
            int n = t >> 8, k = t & 255;
            wt3[n * 256 + k] = f2bf(W3[k * 256 + n]);
        }
    }
}

// ---------------- KNN scan: branchless fp32, chunk-major output (coalesced) --------
__global__ __launch_bounds__(256) void knn_scan_kernel(
    const float* __restrict__ pts, const float4* __restrict__ kp4,
    float4* __restrict__ pb4)
{
    int tid = threadIdx.x;
    int n = blockIdx.x * 256 + tid;
    int c = blockIdx.y;
    int v0 = c * CHUNK;
    int v1 = min(V_N, v0 + CHUNK);

    float px2 = 2.0f * pts[n*6+0], py2 = 2.0f * pts[n*6+1], pz2 = 2.0f * pts[n*6+2];

    float m1 = 1e30f, m2 = 1e30f;
    int bi = 0x7fffffff;

#define KNN_STEP(kk, jj)                                            \
    {                                                               \
        float d = kk.w - (px2*kk.x + py2*kk.y + pz2*kk.z);          \
        bool lt = d < m1;                                           \
        m2 = lt ? m1 : fminf(m2, d);                                \
        bi = lt ? (jj) : bi;                                        \
        m1 = fminf(m1, d);                                          \
    }

    int j = v0;
    for (; j + 4 <= v1; j += 4) {
        float4 k0 = kp4[j], k1 = kp4[j+1], k2 = kp4[j+2], k3 = kp4[j+3];
        KNN_STEP(k0, j); KNN_STEP(k1, j+1); KNN_STEP(k2, j+2); KNN_STEP(k3, j+3);
    }
    for (; j < v1; ++j) {
        float4 k0 = kp4[j];
        KNN_STEP(k0, j);
    }
#undef KNN_STEP

    pb4[(size_t)c*N_PTS + n] = make_float4(m1, m2, __int_as_float(bi), 0.0f);
}

// ---------------- KNN reduce: merge chunks, certify gap, flag ambiguous --------
__global__ __launch_bounds__(256) void knn_reduce_kernel(
    const float4* __restrict__ pb4, int* __restrict__ knn,
    int* __restrict__ cnt, int* __restrict__ flag_list)
{
    int n = blockIdx.x * 256 + threadIdx.x;
    float m1 = 1e30f, m2 = 1e30f;
    int bi = 0x7fffffff;
#pragma unroll
    for (int c = 0; c < NCHUNK; ++c) {
        float4 P = pb4[(size_t)c*N_PTS + n];   // coalesced
        float b = P.x, b2 = P.y;
        int i = __float_as_int(P.z);
        float mx = fmaxf(m1, b);
        m2 = fminf(fminf(m2, b2), mx);
        bi = (b < m1) ? i : bi;      // ascending c => equal keeps lower chunk
        m1 = fminf(m1, b);
    }
    knn[n] = bi;
    if (m2 - m1 < GAP_EPS) {
        int s = atomicAdd(cnt, 1);
        flag_list[s] = n;
    }
}

// ---------------- KNN exact: fp64 rescan, one wave per flagged point (R6-proven) ----
__global__ __launch_bounds__(256) void knn_exact_kernel(
    const float* __restrict__ pts, const float4* __restrict__ kp4,
    const int* __restrict__ cnt, const int* __restrict__ flag_list,
    int* __restrict__ knn)
{
    int lane = threadIdx.x & 63;
    int gwave = (blockIdx.x * 256 + threadIdx.x) >> 6;
    int nwaves = gridDim.x * 4;
    int total = cnt[0];

    for (int it = gwave; it < total; it += nwaves) {
        int n = flag_list[it];
        double pxd = (double)pts[n*6+0], pyd = (double)pts[n*6+1], pzd = (double)pts[n*6+2];
        double ppd = pxd*pxd + pyd*pyd + pzd*pzd;
        double best = 1e300; int bi = 0x7fffffff;
        for (int j = lane; j < V_N; j += 64) {
            float4 k = kp4[j];
            double kx = (double)k.x, ky = (double)k.y, kz = (double)k.z;
            double d = ppd - 2.0*(pxd*kx + pyd*ky + pzd*kz) + (kx*kx + ky*ky + kz*kz);
            if (d < best || (d == best && j < bi)) { best = d; bi = j; }
        }
#pragma unroll
        for (int off = 32; off >= 1; off >>= 1) {
            double od = __shfl_xor(best, off);
            int    oi = __shfl_xor(bi, off);
            if (od < best || (od == best && oi < bi)) { best = od; bi = oi; }
        }
        if (lane == 0) knn[n] = bi;
    }
}

// ---------------- features v4: 4 points/wave, all loads in phase A ----------------
// Phase A (parallel vector gathers, no scalar chain): lanes (p=lane>>4, j=lane&15);
// j<7 gathers neigh/kp4/rp4 -> vf; j==7 gathers kp4[k]+rinv4[k] and computes dir.
// Phase B: zero global loads except the latent gather -- LDS broadcasts + HW
// sin/cos + coalesced stores. 4096 waves (4/SIMD) for latency hiding.
__global__ __launch_bounds__(256) void feat_kernel(
    const float* __restrict__ pts, const int* __restrict__ neigh,
    const float* __restrict__ latent, const float4* __restrict__ rinv4,
    const float4* __restrict__ kp4, const float4* __restrict__ rp4,
    const int* __restrict__ knn, unsigned short* __restrict__ X,
    float* __restrict__ out)
{
    __shared__ float s_vf[4][4][29];   // [wave][point][28+pad] = 1.9 KB
    __shared__ float s_dir[4][4][4];   // 256 B

    int t = threadIdx.x;
    int w = t >> 6, lane = t & 63;
    int p = lane >> 4, j = lane & 15;
    int n0 = blockIdx.x * 16 + w * 4;   // first point of this wave
    int np = n0 + p;

    // Phase A: batched gathers (4 points in parallel)
    int k8 = knn[np];
    float px = pts[np*6+0], py = pts[np*6+1], pz = pts[np*6+2];

    int v7 = 0;
    if (j < 7) {
        v7 = neigh[k8*7 + j];
        float4 kq = kp4[v7];
        float4 rq = rp4[v7];
        float dx = px - kq.x, dy = py - kq.y, dz = pz - kq.z;
        s_vf[w][p][j*3+0] = rq.x;
        s_vf[w][p][j*3+1] = rq.y;
        s_vf[w][p][j*3+2] = rq.z;
        s_vf[w][p][21+j]  = sqrtf(dx*dx + dy*dy + dz*dz);
    } else if (j == 7) {
        float4 kq = kp4[k8];
        float ddx = px - kq.x, ddy = py - kq.y, ddz = pz - kq.z;
        float4 R0 = rinv4[k8*3+0];
        float4 R1 = rinv4[k8*3+1];
        float4 R2 = rinv4[k8*3+2];
        float d0 = R0.x*ddx + R0.y*ddy + R0.z*ddz;
        float d1 = R0.w*ddx + R1.x*ddy + R1.y*ddz;
        float d2 = R1.z*ddx + R1.w*ddy + R2.x*ddz;
        float nrm = fmaxf(sqrtf(d0*d0 + d1*d1 + d2*d2), 1e-12f);
        s_dir[w][p][0] = d0/nrm; s_dir[w][p][1] = d1/nrm; s_dir[w][p][2] = d2/nrm;
    }
    // no barrier: each wave reads only its own LDS rows (intra-wave lgkmcnt)

    // Phase B: per-point posenc + stores (no global/scalar loads except latent)
#pragma unroll
    for (int pp = 0; pp < 4; ++pp) {
        int n = n0 + pp;                                   // wave-uniform
        float dir0 = s_dir[w][pp][0];                      // LDS broadcasts
        float dir1 = s_dir[w][pp][1];
        float dir2 = s_dir[w][pp][2];

        // output tail (fp32): [dir(3), sin f-major (12), cos (12)]
        if (lane < 27) {
            float val;
            if (lane < 3) {
                val = (lane == 0) ? dir0 : (lane == 1) ? dir1 : dir2;
            } else {
                int tt = (lane < 15) ? lane - 3 : lane - 15;
                int m = tt % 3;
                float db = (m == 0) ? dir0 : (m == 1) ? dir1 : dir2;
                float a = db * (float)(1 << (tt/3));
                val = (lane < 15) ? fsin(a) : fcos(a);
            }
            out[(size_t)n*D_OUT + 256 + lane] = val;
        }

        // X row bf16, quad-per-lane; vf from wave-private LDS (broadcast-heavy)
#pragma unroll
        for (int it = 0; it < 3; ++it) {
            int base = it * 256 + (lane << 2);
            bool in_range = base < D_INP;
            int region = (base < 28) ? 0 : (base < 308) ? 1 : (base < 588) ? 2
                       : (base < 700) ? 3 : 4;

            int t0 = (region == 1) ? base - 28 : (region == 2) ? base - 308 : 0;
            int q = t0 / 28;
            int r = t0 - q * 28;
            float f0 = (float)(1 << q);
            float a[4];
#pragma unroll
            for (int jj = 0; jj < 4; ++jj) {
                int rj; float fj;
                if (region == 0) { rj = base + jj; fj = 1.0f; }
                else if (region <= 2) {
                    rj = r + jj; fj = f0;
                    if (rj >= 28) { rj -= 28; fj = f0 * 2.0f; }
                } else { rj = 0; fj = 0.0f; }
                a[jj] = s_vf[w][pp][rj] * fj;       // ds_read_b32
            }
            // latent neighbor index via full-exec shuffle (v7 valid at lanes pp*16+0..6)
            int idxc = (region == 3) ? (base - 588) >> 4 : 0;
            int vL = __shfl(v7, pp*16 + idxc);

            unsigned short r0, r1, r2, r3;
            if (region == 0) {
                r0 = f2bf(a[0]); r1 = f2bf(a[1]); r2 = f2bf(a[2]); r3 = f2bf(a[3]);
            } else if (region == 1) {
                r0 = f2bf(fsin(a[0])); r1 = f2bf(fsin(a[1]));
                r2 = f2bf(fsin(a[2])); r3 = f2bf(fsin(a[3]));
            } else if (region == 2) {
                r0 = f2bf(fcos(a[0])); r1 = f2bf(fcos(a[1]));
                r2 = f2bf(fcos(a[2])); r3 = f2bf(fcos(a[3]));
            } else if (region == 3) {
                int t3 = base - 588;
                float4 lv = *(const float4*)&latent[vL * 16 + (t3 & 15)];
                r0 = f2bf(lv.x); r1 = f2bf(lv.y); r2 = f2bf(lv.z); r3 = f2bf(lv.w);
            } else {
                r0 = r1 = r2 = r3 = 0;
            }
            if (in_range)
                *(ushort4*)&X[(size_t)n * D_INP + base] = make_ushort4(r0, r1, r2, r3);
        }
    }
}

// ---------------- fused 3-layer MLP: 64 rows/block through all layers ----------------
#define HLD 264
__global__ __launch_bounds__(512) void mlp_kernel(
    const unsigned short* __restrict__ X,
    const unsigned short* __restrict__ wt1,
    const unsigned short* __restrict__ wt2,
    const unsigned short* __restrict__ wt3,
    const float* __restrict__ b1, const float* __restrict__ b2,
    const float* __restrict__ b3, float* __restrict__ out)
{
    __shared__ unsigned short As[64 * 32];     // 4 KB
    __shared__ unsigned short Ws[256 * 32];    // 16 KB
    __shared__ unsigned short H1[64 * HLD];    // 33 KB
    __shared__ unsigned short H2[64 * HLD];    // 33 KB

    int t = threadIdx.x, l = t & 63, w = t >> 6;
    int bm = blockIdx.x * 64;
    int mbase = (w >> 2) * 32, nbase = (w & 3) * 64;
    int lrow = l & 15, lk = (l >> 4) * 8;
    int col0 = l & 15, rquad = (l >> 4) * 4;

    f32x4 acc[2][4];
    short8 af[2], bf[4];

    // layer 1: X[704] @ wt1^T -> relu -> H1
#pragma unroll
    for (int mi = 0; mi < 2; ++mi)
#pragma unroll
        for (int ni = 0; ni < 4; ++ni) acc[mi][ni] = {0.f, 0.f, 0.f, 0.f};

    for (int k0 = 0; k0 < D_INP; k0 += 32) {
        if (t < 256)
            glds16(X + (size_t)(bm + (t >> 2)) * D_INP + k0 + (t & 3) * 8,
                   (char*)As + t * 16);
#pragma unroll
        for (int i = 0; i < 2; ++i) {
            int c = i * 512 + t;
            glds16(wt1 + (size_t)(c >> 2) * D_INP + k0 + (c & 3) * 8,
                   (char*)Ws + (size_t)c * 16);
        }
        __syncthreads();
#pragma unroll
        for (int mi = 0; mi < 2; ++mi)
            af[mi] = *(const short8*)&As[(mbase + mi * 16 + lrow) * 32 + lk];
#pragma unroll
        for (int ni = 0; ni < 4; ++ni)
            bf[ni] = *(const short8*)&Ws[(nbase + ni * 16 + lrow) * 32 + lk];
#pragma unroll
        for (int mi = 0; mi < 2; ++mi)
#pragma unroll
            for (int ni = 0; ni < 4; ++ni)
                acc[mi][ni] = __builtin_amdgcn_mfma_f32_16x16x32_bf16(
                    af[mi], bf[ni], acc[mi][ni], 0, 0, 0);
        __syncthreads();
    }
#pragma unroll
    for (int mi = 0; mi < 2; ++mi)
#pragma unroll
        for (int ni = 0; ni < 4; ++ni) {
            int col = nbase + ni * 16 + col0;
            float bv = b1[col];
#pragma unroll
            for (int r = 0; r < 4; ++r) {
                int row = mbase + mi * 16 + rquad + r;
                H1[row * HLD + col] = f2bf(fmaxf(acc[mi][ni][r] + bv, 0.0f));
            }
        }
    __syncthreads();

    // layer 2: H1 @ wt2^T -> relu -> H2
#pragma unroll
    for (int mi = 0; mi < 2; ++mi)
#pragma unroll
        for (int ni = 0; ni < 4; ++ni) acc[mi][ni] = {0.f, 0.f, 0.f, 0.f};

    for (int k0 = 0; k0 < D_HID; k0 += 32) {
#pragma unroll
        for (int i = 0; i < 2; ++i) {
            int c = i * 512 + t;
            glds16(wt2 + (size_t)(c >> 2) * D_HID + k0 + (c & 3) * 8,
                   (char*)Ws + (size_t)c * 16);
        }
        __syncthreads();
#pragma unroll
        for (int mi = 0; mi < 2; ++mi)
            af[mi] = *(const short8*)&H1[(mbase + mi * 16 + lrow) * HLD + k0 + lk];
#pragma unroll
        for (int ni = 0; ni < 4; ++ni)
            bf[ni] = *(const short8*)&Ws[(nbase + ni * 16 + lrow) * 32 + lk];
#pragma unroll
        for (int mi = 0; mi < 2; ++mi)
#pragma unroll
            for (int ni = 0; ni < 4; ++ni)
                acc[mi][ni] = __builtin_amdgcn_mfma_f32_16x16x32_bf16(
                    af[mi], bf[ni], acc[mi][ni], 0, 0, 0);
        __syncthreads();
    }
#pragma unroll
    for (int mi = 0; mi < 2; ++mi)
#pragma unroll
        for (int ni = 0; ni < 4; ++ni) {
            int col = nbase + ni * 16 + col0;
            float bv = b2[col];
#pragma unroll
            for (int r = 0; r < 4; ++r) {
                int row = mbase + mi * 16 + rquad + r;
                H2[row * HLD + col] = f2bf(fmaxf(acc[mi][ni][r] + bv, 0.0f));
            }
        }
    __syncthreads();

    // layer 3: H2 @ wt3^T + b3 -> out (fp32)
#pragma unroll
    for (int mi = 0; mi < 2; ++mi)
#pragma unroll
        for (int ni = 0; ni < 4; ++ni) acc[mi][ni] = {0.f, 0.f, 0.f, 0.f};

    for (int k0 = 0; k0 < D_HID; k0 += 32) {
#pragma unroll
        for (int i = 0; i < 2; ++i) {
            int c = i * 512 + t;
            glds16(wt3 + (size_t)(c >> 2) * D_HID + k0 + (c & 3) * 8,
                   (char*)Ws + (size_t)c * 16);
        }
        __syncthreads();
#pragma unroll
        for (int mi = 0; mi < 2; ++mi)
            af[mi] = *(const short8*)&H2[(mbase + mi * 16 + lrow) * HLD + k0 + lk];
#pragma unroll
        for (int ni = 0; ni < 4; ++ni)
            bf[ni] = *(const short8*)&Ws[(nbase + ni * 16 + lrow) * 32 + lk];
#pragma unroll
        for (int mi = 0; mi < 2; ++mi)
#pragma unroll
            for (int ni = 0; ni < 4; ++ni)
                acc[mi][ni] = __builtin_amdgcn_mfma_f32_16x16x32_bf16(
                    af[mi], bf[ni], acc[mi][ni], 0, 0, 0);
        __syncthreads();
    }
#pragma unroll
    for (int mi = 0; mi < 2; ++mi)
#pragma unroll
        for (int ni = 0; ni < 4; ++ni) {
            int col = nbase + ni * 16 + col0;
            float bv = b3[col];
#pragma unroll
            for (int r = 0; r < 4; ++r) {
                int row = bm + mbase + mi * 16 + rquad + r;
                out[(size_t)row * D_OUT + col] = acc[mi][ni][r] + bv;
            }
        }
}

extern "C" void kernel_launch(void* const* d_in, const int* in_sizes, int n_in,
                              void* d_out, int out_size, void* d_ws, size_t ws_size,
                              hipStream_t stream) {
    const float* pts    = (const float*)d_in[0];
    const float* keyp   = (const float*)d_in[1];
    const float* trans  = (const float*)d_in[2];
    const int*   neigh  = (const int*)d_in[3];
    const float* restp  = (const float*)d_in[4];
    const float* latent = (const float*)d_in[5];
    const float* W1     = (const float*)d_in[6];
    const float* b1     = (const float*)d_in[7];
    const float* W2     = (const float*)d_in[8];
    const float* b2     = (const float*)d_in[9];
    const float* W3     = (const float*)d_in[10];
    const float* b3     = (const float*)d_in[11];
    float* out = (float*)d_out;

    float* wsf = (float*)d_ws;
    float4*         rinv4 = (float4*)(wsf + RINV4_OFF);
    float4*         kp4   = (float4*)(wsf + KP4_OFF);
    float4*         rp4   = (float4*)(wsf + RP4_OFF);
    int*            knn   = (int*)(wsf + KNN_OFF);
    int*            cnt   = (int*)(wsf + CNT_OFF);
    int*            flg   = (int*)(wsf + FLAG_OFF);
    float4*         pb4   = (float4*)(wsf + PB4_OFF);
    unsigned short* wt1   = (unsigned short*)(wsf + WT1_OFF);
    unsigned short* wt2   = (unsigned short*)(wsf + WT2_OFF);
    unsigned short* wt3   = (unsigned short*)(wsf + WT3_OFF);
    unsigned short* X     = (unsigned short*)(wsf + X_OFF);

    int wconv_blocks = (256*D_INP + 2*256*256 + 255) / 256;
    prep_wconv_kernel<<<PREP_BLOCKS + wconv_blocks, 256, 0, stream>>>(
        trans, keyp, restp, rinv4, kp4, rp4, W1, W2, W3, wt1, wt2, wt3, cnt);
    knn_scan_kernel<<<dim3(N_PTS/256, NCHUNK), 256, 0, stream>>>(pts, kp4, pb4);
    knn_reduce_kernel<<<N_PTS/256, 256, 0, stream>>>(pb4, knn, cnt, flg);
    knn_exact_kernel<<<128, 256, 0, stream>>>(pts, kp4, cnt, flg, knn);
    feat_kernel<<<N_PTS/16, 256, 0, stream>>>(pts, neigh, latent, rinv4,
                                              kp4, rp4, knn, X, out);
    mlp_kernel<<<N_PTS/64, 512, 0, stream>>>(X, wt1, wt2, wt3, b1, b2, b3, out);
}